// Round 8
// baseline (113.225 us; speedup 1.0000x reference)
//
#include <hip/hip_runtime.h>

#define SIZE 1024
#define MM 10
#define NTERMS 10

typedef _Float16 f16;
typedef __attribute__((ext_vector_type(8))) _Float16 f16x8;
typedef __attribute__((ext_vector_type(4))) _Float16 f16x4;
typedef __attribute__((ext_vector_type(4))) float    f32x4;
typedef __attribute__((ext_vector_type(2))) int      i2;

__device__ __forceinline__ float4 ldq(const float* p) { return *(const float4*)p; }

#define FMA4F(W, v0, v1, v2, v3)                                     \
    a0 = fmaf((W)[0], (v0), a0); a1 = fmaf((W)[1], (v1), a1);        \
    a2 = fmaf((W)[2], (v2), a2); a3 = fmaf((W)[3], (v3), a3);

// ===========================================================================
// Phase 1: G = A^T (out = x @ G). R0-proven fp32 stencil body applied to the
// identity. RPB=8 rows/block -> 128 blocks (R8: was 512x2 — quarters the
// term-invariant coef reload traffic through L2).
// ===========================================================================
#define PRB 8
__global__ __launch_bounds__(256, 2)
void precompute_G(const float* __restrict__ diag,
                  const float* __restrict__ subpad,
                  const float* __restrict__ suppad,
                  const float* __restrict__ logit,
                  float* __restrict__ G)
{
    __shared__ float buf[2][PRB][SIZE];   // 64 KB

    const int tid = threadIdx.x;
    const int s0  = tid * 4;
    const int rowbase = blockIdx.x * PRB; // 128 blocks x 8 rows = 1024

    #pragma unroll
    for (int r = 0; r < PRB; ++r) {
        float4 v;
        v.x = (rowbase + r == s0 + 0) ? 1.f : 0.f;
        v.y = (rowbase + r == s0 + 1) ? 1.f : 0.f;
        v.z = (rowbase + r == s0 + 2) ? 1.f : 0.f;
        v.w = (rowbase + r == s0 + 3) ? 1.f : 0.f;
        *(float4*)&buf[0][r][s0] = v;
    }
    __syncthreads();

    int cur = 0;
    for (int t = 0; t < NTERMS; ++t) {
        const int i = NTERMS - 1 - t;

        float lg[MM];
        float mx = -3.4e38f;
        #pragma unroll
        for (int j = 0; j < MM; ++j) { lg[j] = logit[i * MM + j]; mx = fmaxf(mx, lg[j]); }
        float ssum = 0.f;
        #pragma unroll
        for (int j = 0; j < MM; ++j) { lg[j] = __expf(lg[j] - mx); ssum += lg[j]; }
        const float inv = 1.0f / ssum;

        float D[4] = {0.f, 0.f, 0.f, 0.f};
        float Wsb[MM][4], Wsp[MM][4];
        #pragma unroll
        for (int j = 0; j < MM; ++j) {
            const float pj = lg[j] * inv;
            const float4 dg = ldq(diag   + j * SIZE + s0);
            const float4 sb = ldq(subpad + j * SIZE + s0);
            const float4 sp = ldq(suppad + j * SIZE + s0);
            D[0] = fmaf(pj, dg.x, D[0]); D[1] = fmaf(pj, dg.y, D[1]);
            D[2] = fmaf(pj, dg.z, D[2]); D[3] = fmaf(pj, dg.w, D[3]);
            Wsb[j][0] = pj * sb.x; Wsb[j][1] = pj * sb.y;
            Wsb[j][2] = pj * sb.z; Wsb[j][3] = pj * sb.w;
            Wsp[j][0] = pj * sp.x; Wsp[j][1] = pj * sp.y;
            Wsp[j][2] = pj * sp.z; Wsp[j][3] = pj * sp.w;
        }

        const bool last = (t == NTERMS - 1);
        for (int r = 0; r < PRB; ++r) {
            const float* row = &buf[cur][r][0];

            const float4 xo = ldq(row + s0);
            float a0 = D[0] * xo.x, a1 = D[1] * xo.y,
                  a2 = D[2] * xo.z, a3 = D[3] * xo.w;

            const float4 xl = ldq(row + (s0 >= 4         ? s0 - 4 : 0));
            const float4 xr = ldq(row + (s0 + 4 <= 1020  ? s0 + 4 : 1020));

            FMA4F(Wsb[9], xl.w, xo.x, xo.y, xo.z)
            FMA4F(Wsp[9], xo.y, xo.z, xo.w, xr.x)
            FMA4F(Wsb[8], xl.z, xl.w, xo.x, xo.y)
            FMA4F(Wsp[8], xo.z, xo.w, xr.x, xr.y)
            FMA4F(Wsb[7], xl.x, xl.y, xl.z, xl.w)
            FMA4F(Wsp[7], xr.x, xr.y, xr.z, xr.w)
            #pragma unroll
            for (int j = 0; j <= 6; ++j) {
                const int d = 512 >> j;
                const float4 xm = ldq(row + (s0 >= d        ? s0 - d : 0));
                const float4 xp = ldq(row + (s0 + d <= 1020 ? s0 + d : 1020));
                FMA4F(Wsb[j], xm.x, xm.y, xm.z, xm.w)
                FMA4F(Wsp[j], xp.x, xp.y, xp.z, xp.w)
            }

            if (last) {
                *(float4*)(G + (long)(rowbase + r) * SIZE + s0) =
                    make_float4(a0, a1, a2, a3);
            } else {
                *(float4*)&buf[cur ^ 1][r][s0] = make_float4(a0, a1, a2, a3);
            }
        }
        __syncthreads();
        cur ^= 1;
    }
}

// ===========================================================================
// Phase 2: Gt[s][k] = (f16) G[k][s]
// ===========================================================================
__global__ __launch_bounds__(256)
void transpose_cast(const float* __restrict__ G, f16* __restrict__ Gt)
{
    __shared__ float tile[64][65];
    const int tid = threadIdx.x;
    const int k0 = blockIdx.x * 64;
    const int s0 = blockIdx.y * 64;
    const int rr = tid >> 4;
    const int cc = (tid & 15) * 4;

    #pragma unroll
    for (int p = 0; p < 4; ++p) {
        const float4 v = ldq(G + (long)(k0 + rr + p * 16) * SIZE + s0 + cc);
        *(float4*)&tile[rr + p * 16][cc] = v;
    }
    __syncthreads();
    #pragma unroll
    for (int p = 0; p < 4; ++p) {
        const int s = rr + p * 16;
        f16x4 h;
        h[0] = (f16)tile[cc + 0][s];
        h[1] = (f16)tile[cc + 1][s];
        h[2] = (f16)tile[cc + 2][s];
        h[3] = (f16)tile[cc + 3][s];
        *(f16x4*)(Gt + (long)(s0 + s) * SIZE + k0 + cc) = h;
    }
}

// ===========================================================================
// Phase 3 (R8 redesign): out = x @ G, BM=BN=128, BK=32, 4 waves (2x2),
// wave tile 64x64 = 4x4 frags of mfma_f32_16x16x32_f16.
//  * B frags load DIRECTLY from global (Gt is 2MB, L2-resident on every
//    XCD), double-buffered in NAMED registers across kt (static indexing).
//    -> no Gs LDS staging at all; barrier only guards A staging.
//  * A staged fp32->f16 into LDS padded to 36 f16/row: frag-read banks
//    18*row mod 32 = 16 distinct; staging writes 2-way (free).
// Same cvt/MFMA/K-order as R7 -> identical numerics (absmax 0.0625).
// ===========================================================================
#define BMT 128
#define BNT 128
#define BKT 32
#define PADK 36
#define NKT (1024 / BKT)

__device__ __forceinline__ void cvt16(const float4& v0, const float4& v1, f16x8& h) {
    h[0] = (f16)v0.x; h[1] = (f16)v0.y; h[2] = (f16)v0.z; h[3] = (f16)v0.w;
    h[4] = (f16)v1.x; h[5] = (f16)v1.y; h[6] = (f16)v1.z; h[7] = (f16)v1.w;
}

__global__ __launch_bounds__(256, 2)
void gemm_f16(const float* __restrict__ x,
              const f16* __restrict__ Gt,
              float* __restrict__ out)
{
    __shared__ f16 Xs[2][BMT][PADK];   // 18 KB

    const int tid  = threadIdx.x;
    const int bm   = blockIdx.x >> 3;          // 64 M-tiles
    const int bn   = blockIdx.x & 7;           // 8  N-tiles
    const int w    = tid >> 6, lane = tid & 63;
    const int wm   = w >> 1,  wn   = w & 1;
    const int lr   = lane & 15, lk = lane >> 4;

    // A staging map: thread t -> row t>>1, k-half (t&1)*16
    const int sr = tid >> 1;
    const int sk = (tid & 1) * 16;
    const float* xrow = x + (long)(bm * BMT + sr) * 1024 + sk;

    // B frag base: lane -> row n = bn*128 + wn*64 + lr (+ni*16), k = lk*8 (+kt*32)
    const f16* gbase = Gt + (long)(bn * BNT + wn * 64 + lr) * 1024 + lk * 8;

    f32x4 acc[4][4];
    #pragma unroll
    for (int mi = 0; mi < 4; ++mi)
        #pragma unroll
        for (int ni = 0; ni < 4; ++ni)
            acc[mi][ni] = (f32x4){0.f, 0.f, 0.f, 0.f};

    float4 v0, v1, v2, v3;             // A stage regs
    f16x8 b0, b1, b2, b3;              // B frags (even kt)
    f16x8 c0, c1, c2, c3;              // B frags (odd kt)

#define LOAD_A(KT) {                                                  \
        const float* xp = xrow + (KT) * BKT;                          \
        v0 = ldq(xp); v1 = ldq(xp + 4);                               \
        v2 = ldq(xp + 8); v3 = ldq(xp + 12); }
#define WRITE_A(BUF) {                                                \
        f16x8 h0, h1; cvt16(v0, v1, h0); cvt16(v2, v3, h1);           \
        *(f16x8*)&Xs[BUF][sr][sk]     = h0;                           \
        *(f16x8*)&Xs[BUF][sr][sk + 8] = h1; }
#define LOAD_B(B0, B1, B2, B3, KT) {                                  \
        const f16* gp = gbase + (KT) * BKT;                           \
        B0 = *(const f16x8*)(gp);                                     \
        B1 = *(const f16x8*)(gp + 16 * 1024);                         \
        B2 = *(const f16x8*)(gp + 32 * 1024);                         \
        B3 = *(const f16x8*)(gp + 48 * 1024); }
#define COMPUTE(BUF, B0, B1, B2, B3) {                                \
        f16x8 a0 = *(const f16x8*)&Xs[BUF][wm * 64 +  0 + lr][lk * 8];\
        f16x8 a1 = *(const f16x8*)&Xs[BUF][wm * 64 + 16 + lr][lk * 8];\
        f16x8 a2 = *(const f16x8*)&Xs[BUF][wm * 64 + 32 + lr][lk * 8];\
        f16x8 a3 = *(const f16x8*)&Xs[BUF][wm * 64 + 48 + lr][lk * 8];\
        acc[0][0] = __builtin_amdgcn_mfma_f32_16x16x32_f16(a0, B0, acc[0][0], 0, 0, 0); \
        acc[0][1] = __builtin_amdgcn_mfma_f32_16x16x32_f16(a0, B1, acc[0][1], 0, 0, 0); \
        acc[0][2] = __builtin_amdgcn_mfma_f32_16x16x32_f16(a0, B2, acc[0][2], 0, 0, 0); \
        acc[0][3] = __builtin_amdgcn_mfma_f32_16x16x32_f16(a0, B3, acc[0][3], 0, 0, 0); \
        acc[1][0] = __builtin_amdgcn_mfma_f32_16x16x32_f16(a1, B0, acc[1][0], 0, 0, 0); \
        acc[1][1] = __builtin_amdgcn_mfma_f32_16x16x32_f16(a1, B1, acc[1][1], 0, 0, 0); \
        acc[1][2] = __builtin_amdgcn_mfma_f32_16x16x32_f16(a1, B2, acc[1][2], 0, 0, 0); \
        acc[1][3] = __builtin_amdgcn_mfma_f32_16x16x32_f16(a1, B3, acc[1][3], 0, 0, 0); \
        acc[2][0] = __builtin_amdgcn_mfma_f32_16x16x32_f16(a2, B0, acc[2][0], 0, 0, 0); \
        acc[2][1] = __builtin_amdgcn_mfma_f32_16x16x32_f16(a2, B1, acc[2][1], 0, 0, 0); \
        acc[2][2] = __builtin_amdgcn_mfma_f32_16x16x32_f16(a2, B2, acc[2][2], 0, 0, 0); \
        acc[2][3] = __builtin_amdgcn_mfma_f32_16x16x32_f16(a2, B3, acc[2][3], 0, 0, 0); \
        acc[3][0] = __builtin_amdgcn_mfma_f32_16x16x32_f16(a3, B0, acc[3][0], 0, 0, 0); \
        acc[3][1] = __builtin_amdgcn_mfma_f32_16x16x32_f16(a3, B1, acc[3][1], 0, 0, 0); \
        acc[3][2] = __builtin_amdgcn_mfma_f32_16x16x32_f16(a3, B2, acc[3][2], 0, 0, 0); \
        acc[3][3] = __builtin_amdgcn_mfma_f32_16x16x32_f16(a3, B3, acc[3][3], 0, 0, 0); }

    // prologue: A(0) -> LDS buf0, B(0) -> b regs
    LOAD_A(0); WRITE_A(0); LOAD_B(b0, b1, b2, b3, 0);
    __syncthreads();

    #pragma unroll 1
    for (int kt2 = 0; kt2 < NKT / 2; ++kt2) {
        const int kt = kt2 * 2;
        // even step: compute buf0 with b; prefetch kt+1 (A->buf1, B->c)
        LOAD_A(kt + 1);
        LOAD_B(c0, c1, c2, c3, kt + 1);
        COMPUTE(0, b0, b1, b2, b3);
        WRITE_A(1);
        __syncthreads();
        // odd step: compute buf1 with c; prefetch kt+2 (A->buf0, B->b)
        if (kt2 < NKT / 2 - 1) {
            LOAD_A(kt + 2);
            LOAD_B(b0, b1, b2, b3, kt + 2);
        }
        COMPUTE(1, c0, c1, c2, c3);
        if (kt2 < NKT / 2 - 1) {
            WRITE_A(0);
        }
        __syncthreads();
    }

    // epilogue: D lane l,q -> row (l>>4)*4+q, col l&15   (R7-verified)
    const long orow0 = (long)bm * BMT + wm * 64 + lk * 4;
    const int  ocol0 = bn * BNT + wn * 64 + lr;
    #pragma unroll
    for (int mi = 0; mi < 4; ++mi)
        #pragma unroll
        for (int ni = 0; ni < 4; ++ni)
            #pragma unroll
            for (int q = 0; q < 4; ++q)
                out[(orow0 + mi * 16 + q) * 1024 + ocol0 + ni * 16] = acc[mi][ni][q];

#undef LOAD_A
#undef WRITE_A
#undef LOAD_B
#undef COMPUTE
}

// ===========================================================================
// Fallback (ws too small): R6's proven stencil kernel.
// ===========================================================================
#define RPB 16
#define MIX_L(acc, r32, ww) \
    asm("v_fma_mix_f32 %0, %1, %2, %0 op_sel:[0,0,0] op_sel_hi:[1,0,0]" \
        : "+v"(acc) : "v"(r32), "v"(ww))
#define MIX_H(acc, r32, ww) \
    asm("v_fma_mix_f32 %0, %1, %2, %0 op_sel:[1,0,0] op_sel_hi:[1,0,0]" \
        : "+v"(acc) : "v"(r32), "v"(ww))

__global__ __launch_bounds__(256, 2)
void butterfly_h16mix(const float* __restrict__ x,
                      const float* __restrict__ diag,
                      const float* __restrict__ subpad,
                      const float* __restrict__ suppad,
                      const float* __restrict__ logit,
                      float* __restrict__ out)
{
    __shared__ f16 buf[2][RPB][SIZE];
    const int tid = threadIdx.x;
    const int s0  = tid * 4;
    const long rowbase = (long)blockIdx.x * RPB;

    #pragma unroll
    for (int r = 0; r < RPB; ++r) {
        const float4 v = ldq(x + (rowbase + r) * SIZE + s0);
        f16x4 h;
        h[0] = (f16)v.x; h[1] = (f16)v.y; h[2] = (f16)v.z; h[3] = (f16)v.w;
        *(f16x4*)&buf[0][r][s0] = h;
    }
    __syncthreads();

    int cur = 0;
    for (int t = 0; t < NTERMS; ++t) {
        const int i = NTERMS - 1 - t;
        float lg[MM];
        float mx = -3.4e38f;
        #pragma unroll
        for (int j = 0; j < MM; ++j) { lg[j] = logit[i * MM + j]; mx = fmaxf(mx, lg[j]); }
        float ssum = 0.f;
        #pragma unroll
        for (int j = 0; j < MM; ++j) { lg[j] = __expf(lg[j] - mx); ssum += lg[j]; }
        const float inv = 1.0f / ssum;

        float D[4] = {0.f, 0.f, 0.f, 0.f};
        float Wsb[MM][4], Wsp[MM][4];
        #pragma unroll
        for (int j = 0; j < MM; ++j) {
            const float pj = lg[j] * inv;
            const float4 dg = ldq(diag   + j * SIZE + s0);
            const float4 sb = ldq(subpad + j * SIZE + s0);
            const float4 sp = ldq(suppad + j * SIZE + s0);
            D[0] = fmaf(pj, dg.x, D[0]); D[1] = fmaf(pj, dg.y, D[1]);
            D[2] = fmaf(pj, dg.z, D[2]); D[3] = fmaf(pj, dg.w, D[3]);
            Wsb[j][0] = pj * sb.x; Wsb[j][1] = pj * sb.y;
            Wsb[j][2] = pj * sb.z; Wsb[j][3] = pj * sb.w;
            Wsp[j][0] = pj * sp.x; Wsp[j][1] = pj * sp.y;
            Wsp[j][2] = pj * sp.z; Wsp[j][3] = pj * sp.w;
        }

        const bool last = (t == NTERMS - 1);
        for (int r = 0; r < RPB; ++r) {
            const f16* row = &buf[cur][r][0];
            const i2 xo = *(const i2*)&row[s0];
            const i2 xl = *(const i2*)&row[(s0 >= 4)        ? s0 - 4 : 0];
            const i2 xr = *(const i2*)&row[(s0 + 4 <= 1020) ? s0 + 4 : 1020];
            float a0 = 0.f, a1 = 0.f, a2 = 0.f, a3 = 0.f;

            MIX_L(a0, xo.x, D[0]); MIX_H(a1, xo.x, D[1]);
            MIX_L(a2, xo.y, D[2]); MIX_H(a3, xo.y, D[3]);
            MIX_H(a0, xl.y, Wsb[9][0]); MIX_L(a1, xo.x, Wsb[9][1]);
            MIX_H(a2, xo.x, Wsb[9][2]); MIX_L(a3, xo.y, Wsb[9][3]);
            MIX_H(a0, xo.x, Wsp[9][0]); MIX_L(a1, xo.y, Wsp[9][1]);
            MIX_H(a2, xo.y, Wsp[9][2]); MIX_L(a3, xr.x, Wsp[9][3]);
            MIX_L(a0, xl.y, Wsb[8][0]); MIX_H(a1, xl.y, Wsb[8][1]);
            MIX_L(a2, xo.x, Wsb[8][2]); MIX_H(a3, xo.x, Wsb[8][3]);
            MIX_L(a0, xo.y, Wsp[8][0]); MIX_H(a1, xo.y, Wsp[8][1]);
            MIX_L(a2, xr.x, Wsp[8][2]); MIX_H(a3, xr.x, Wsp[8][3]);
            MIX_L(a0, xl.x, Wsb[7][0]); MIX_H(a1, xl.x, Wsb[7][1]);
            MIX_L(a2, xl.y, Wsb[7][2]); MIX_H(a3, xl.y, Wsb[7][3]);
            MIX_L(a0, xr.x, Wsp[7][0]); MIX_H(a1, xr.x, Wsp[7][1]);
            MIX_L(a2, xr.y, Wsp[7][2]); MIX_H(a3, xr.y, Wsp[7][3]);
            #pragma unroll
            for (int j = 0; j <= 6; ++j) {
                const int d = 512 >> j;
                const i2 xm = *(const i2*)&row[(s0 >= d)        ? s0 - d : 0];
                const i2 xp = *(const i2*)&row[(s0 + d <= 1020) ? s0 + d : 1020];
                MIX_L(a0, xm.x, Wsb[j][0]); MIX_H(a1, xm.x, Wsb[j][1]);
                MIX_L(a2, xm.y, Wsb[j][2]); MIX_H(a3, xm.y, Wsb[j][3]);
                MIX_L(a0, xp.x, Wsp[j][0]); MIX_H(a1, xp.x, Wsp[j][1]);
                MIX_L(a2, xp.y, Wsp[j][2]); MIX_H(a3, xp.y, Wsp[j][3]);
            }

            if (last) {
                *(float4*)(out + (rowbase + r) * SIZE + s0) =
                    make_float4(a0, a1, a2, a3);
            } else {
                f16x4 hv;
                hv[0] = (f16)a0; hv[1] = (f16)a1; hv[2] = (f16)a2; hv[3] = (f16)a3;
                *(f16x4*)&buf[cur ^ 1][r][s0] = hv;
            }
        }
        __syncthreads();
        cur ^= 1;
    }
}

extern "C" void kernel_launch(void* const* d_in, const int* in_sizes, int n_in,
                              void* d_out, int out_size, void* d_ws, size_t ws_size,
                              hipStream_t stream) {
    const float* x      = (const float*)d_in[0];
    const float* diag   = (const float*)d_in[1];
    const float* subpad = (const float*)d_in[2];
    const float* suppad = (const float*)d_in[3];
    const float* logit  = (const float*)d_in[4];
    float* outp = (float*)d_out;

    const int batch = in_sizes[0] / SIZE;          // 8192
    const size_t needG  = (size_t)SIZE * SIZE * sizeof(float);  // 4 MB
    const size_t needGt = (size_t)SIZE * SIZE * sizeof(f16);    // 2 MB

    if (d_ws != nullptr && ws_size >= needG + needGt) {
        float* G  = (float*)d_ws;
        f16*   Gt = (f16*)((char*)d_ws + needG);
        precompute_G<<<dim3(SIZE / PRB), dim3(256), 0, stream>>>(
            diag, subpad, suppad, logit, G);
        transpose_cast<<<dim3(16, 16), dim3(256), 0, stream>>>(G, Gt);
        const int nblocks = (batch / BMT) * (SIZE / BNT);       // 512
        gemm_f16<<<dim3(nblocks), dim3(256), 0, stream>>>(x, Gt, outp);
    } else {
        butterfly_h16mix<<<dim3(batch / RPB), dim3(256), 0, stream>>>(
            x, diag, subpad, suppad, logit, outp);
    }
}

// Round 9
// 90.699 us; speedup vs baseline: 1.2484x; 1.2484x over previous
//
#include <hip/hip_runtime.h>

#define SIZE 1024
#define MM 10
#define NTERMS 10

typedef _Float16 f16;
typedef __attribute__((ext_vector_type(8))) _Float16 f16x8;
typedef __attribute__((ext_vector_type(4))) _Float16 f16x4;
typedef __attribute__((ext_vector_type(4))) float    f32x4;
typedef __attribute__((ext_vector_type(2))) int      i2;

__device__ __forceinline__ float4 ldq(const float* p) { return *(const float4*)p; }

#define FMA4F(W, v0, v1, v2, v3)                                     \
    a0 = fmaf((W)[0], (v0), a0); a1 = fmaf((W)[1], (v1), a1);        \
    a2 = fmaf((W)[2], (v2), a2); a3 = fmaf((W)[3], (v3), a3);

// ===========================================================================
// Phase 1: G = A^T (out = x @ G). R0-proven fp32 stencil body applied to the
// identity. R9: ONE row per block -> 1024 blocks (~4 blocks/CU at 128 VGPR).
// R8's PRB=8/128-block version was latency-bound at 0.5 blocks/CU (63us,
// Occupancy 5%); the precompute needs TLP, not traffic reduction (R6 already
// disproved the coef-L2 pole).
// ===========================================================================
__global__ __launch_bounds__(256, 2)
void precompute_G(const float* __restrict__ diag,
                  const float* __restrict__ subpad,
                  const float* __restrict__ suppad,
                  const float* __restrict__ logit,
                  float* __restrict__ G)
{
    __shared__ float buf[2][SIZE];        // 8 KB

    const int tid = threadIdx.x;
    const int s0  = tid * 4;
    const int row = blockIdx.x;           // 1024 blocks x 1 identity row

    {
        float4 v;
        v.x = (row == s0 + 0) ? 1.f : 0.f;
        v.y = (row == s0 + 1) ? 1.f : 0.f;
        v.z = (row == s0 + 2) ? 1.f : 0.f;
        v.w = (row == s0 + 3) ? 1.f : 0.f;
        *(float4*)&buf[0][s0] = v;
    }
    __syncthreads();

    int cur = 0;
    for (int t = 0; t < NTERMS; ++t) {
        const int i = NTERMS - 1 - t;

        float lg[MM];
        float mx = -3.4e38f;
        #pragma unroll
        for (int j = 0; j < MM; ++j) { lg[j] = logit[i * MM + j]; mx = fmaxf(mx, lg[j]); }
        float ssum = 0.f;
        #pragma unroll
        for (int j = 0; j < MM; ++j) { lg[j] = __expf(lg[j] - mx); ssum += lg[j]; }
        const float inv = 1.0f / ssum;

        float D[4] = {0.f, 0.f, 0.f, 0.f};
        float Wsb[MM][4], Wsp[MM][4];
        #pragma unroll
        for (int j = 0; j < MM; ++j) {
            const float pj = lg[j] * inv;
            const float4 dg = ldq(diag   + j * SIZE + s0);
            const float4 sb = ldq(subpad + j * SIZE + s0);
            const float4 sp = ldq(suppad + j * SIZE + s0);
            D[0] = fmaf(pj, dg.x, D[0]); D[1] = fmaf(pj, dg.y, D[1]);
            D[2] = fmaf(pj, dg.z, D[2]); D[3] = fmaf(pj, dg.w, D[3]);
            Wsb[j][0] = pj * sb.x; Wsb[j][1] = pj * sb.y;
            Wsb[j][2] = pj * sb.z; Wsb[j][3] = pj * sb.w;
            Wsp[j][0] = pj * sp.x; Wsp[j][1] = pj * sp.y;
            Wsp[j][2] = pj * sp.z; Wsp[j][3] = pj * sp.w;
        }

        const bool last = (t == NTERMS - 1);
        {
            const float* rp = &buf[cur][0];

            const float4 xo = ldq(rp + s0);
            float a0 = D[0] * xo.x, a1 = D[1] * xo.y,
                  a2 = D[2] * xo.z, a3 = D[3] * xo.w;

            const float4 xl = ldq(rp + (s0 >= 4         ? s0 - 4 : 0));
            const float4 xr = ldq(rp + (s0 + 4 <= 1020  ? s0 + 4 : 1020));

            FMA4F(Wsb[9], xl.w, xo.x, xo.y, xo.z)
            FMA4F(Wsp[9], xo.y, xo.z, xo.w, xr.x)
            FMA4F(Wsb[8], xl.z, xl.w, xo.x, xo.y)
            FMA4F(Wsp[8], xo.z, xo.w, xr.x, xr.y)
            FMA4F(Wsb[7], xl.x, xl.y, xl.z, xl.w)
            FMA4F(Wsp[7], xr.x, xr.y, xr.z, xr.w)
            #pragma unroll
            for (int j = 0; j <= 6; ++j) {
                const int d = 512 >> j;
                const float4 xm = ldq(rp + (s0 >= d        ? s0 - d : 0));
                const float4 xp = ldq(rp + (s0 + d <= 1020 ? s0 + d : 1020));
                FMA4F(Wsb[j], xm.x, xm.y, xm.z, xm.w)
                FMA4F(Wsp[j], xp.x, xp.y, xp.z, xp.w)
            }

            if (last) {
                *(float4*)(G + (long)row * SIZE + s0) = make_float4(a0, a1, a2, a3);
            } else {
                *(float4*)&buf[cur ^ 1][s0] = make_float4(a0, a1, a2, a3);
            }
        }
        __syncthreads();
        cur ^= 1;
    }
}

// ===========================================================================
// Phase 2: Gt[s][k] = (f16) G[k][s]
// ===========================================================================
__global__ __launch_bounds__(256)
void transpose_cast(const float* __restrict__ G, f16* __restrict__ Gt)
{
    __shared__ float tile[64][65];
    const int tid = threadIdx.x;
    const int k0 = blockIdx.x * 64;
    const int s0 = blockIdx.y * 64;
    const int rr = tid >> 4;
    const int cc = (tid & 15) * 4;

    #pragma unroll
    for (int p = 0; p < 4; ++p) {
        const float4 v = ldq(G + (long)(k0 + rr + p * 16) * SIZE + s0 + cc);
        *(float4*)&tile[rr + p * 16][cc] = v;
    }
    __syncthreads();
    #pragma unroll
    for (int p = 0; p < 4; ++p) {
        const int s = rr + p * 16;
        f16x4 h;
        h[0] = (f16)tile[cc + 0][s];
        h[1] = (f16)tile[cc + 1][s];
        h[2] = (f16)tile[cc + 2][s];
        h[3] = (f16)tile[cc + 3][s];
        *(f16x4*)(Gt + (long)(s0 + s) * SIZE + k0 + cc) = h;
    }
}

// ===========================================================================
// Phase 3: out = x @ G, BM=BN=128, BK=32, 4 waves (2x2), B from global regs.
// R9 change: bid -> (bm = bid&63, bn = bid>>6). The 8 bn-blocks sharing an
// x-panel then all have bid = bm (mod 8) -> same XCD under round-robin
// dispatch, all concurrent (512 blocks co-resident) -> x-panel is HBM-fetched
// once per chip instead of 8x (R7/R8 FETCH 132-165MB was the GEMM's wall).
// ===========================================================================
#define BMT 128
#define BNT 128
#define BKT 32
#define PADK 36
#define NKT (1024 / BKT)

__device__ __forceinline__ void cvt16(const float4& v0, const float4& v1, f16x8& h) {
    h[0] = (f16)v0.x; h[1] = (f16)v0.y; h[2] = (f16)v0.z; h[3] = (f16)v0.w;
    h[4] = (f16)v1.x; h[5] = (f16)v1.y; h[6] = (f16)v1.z; h[7] = (f16)v1.w;
}

__global__ __launch_bounds__(256, 2)
void gemm_f16(const float* __restrict__ x,
              const f16* __restrict__ Gt,
              float* __restrict__ out)
{
    __shared__ f16 Xs[2][BMT][PADK];   // 18 KB

    const int tid  = threadIdx.x;
    const int bm   = blockIdx.x & 63;          // R9: same-bm -> same XCD
    const int bn   = blockIdx.x >> 6;
    const int w    = tid >> 6, lane = tid & 63;
    const int wm   = w >> 1,  wn   = w & 1;
    const int lr   = lane & 15, lk = lane >> 4;

    const int sr = tid >> 1;
    const int sk = (tid & 1) * 16;
    const float* xrow = x + (long)(bm * BMT + sr) * 1024 + sk;

    const f16* gbase = Gt + (long)(bn * BNT + wn * 64 + lr) * 1024 + lk * 8;

    f32x4 acc[4][4];
    #pragma unroll
    for (int mi = 0; mi < 4; ++mi)
        #pragma unroll
        for (int ni = 0; ni < 4; ++ni)
            acc[mi][ni] = (f32x4){0.f, 0.f, 0.f, 0.f};

    float4 v0, v1, v2, v3;
    f16x8 b0, b1, b2, b3;
    f16x8 c0, c1, c2, c3;

#define LOAD_A(KT) {                                                  \
        const float* xp = xrow + (KT) * BKT;                          \
        v0 = ldq(xp); v1 = ldq(xp + 4);                               \
        v2 = ldq(xp + 8); v3 = ldq(xp + 12); }
#define WRITE_A(BUF) {                                                \
        f16x8 h0, h1; cvt16(v0, v1, h0); cvt16(v2, v3, h1);           \
        *(f16x8*)&Xs[BUF][sr][sk]     = h0;                           \
        *(f16x8*)&Xs[BUF][sr][sk + 8] = h1; }
#define LOAD_B(B0, B1, B2, B3, KT) {                                  \
        const f16* gp = gbase + (KT) * BKT;                           \
        B0 = *(const f16x8*)(gp);                                     \
        B1 = *(const f16x8*)(gp + 16 * 1024);                         \
        B2 = *(const f16x8*)(gp + 32 * 1024);                         \
        B3 = *(const f16x8*)(gp + 48 * 1024); }
#define COMPUTE(BUF, B0, B1, B2, B3) {                                \
        f16x8 a0 = *(const f16x8*)&Xs[BUF][wm * 64 +  0 + lr][lk * 8];\
        f16x8 a1 = *(const f16x8*)&Xs[BUF][wm * 64 + 16 + lr][lk * 8];\
        f16x8 a2 = *(const f16x8*)&Xs[BUF][wm * 64 + 32 + lr][lk * 8];\
        f16x8 a3 = *(const f16x8*)&Xs[BUF][wm * 64 + 48 + lr][lk * 8];\
        acc[0][0] = __builtin_amdgcn_mfma_f32_16x16x32_f16(a0, B0, acc[0][0], 0, 0, 0); \
        acc[0][1] = __builtin_amdgcn_mfma_f32_16x16x32_f16(a0, B1, acc[0][1], 0, 0, 0); \
        acc[0][2] = __builtin_amdgcn_mfma_f32_16x16x32_f16(a0, B2, acc[0][2], 0, 0, 0); \
        acc[0][3] = __builtin_amdgcn_mfma_f32_16x16x32_f16(a0, B3, acc[0][3], 0, 0, 0); \
        acc[1][0] = __builtin_amdgcn_mfma_f32_16x16x32_f16(a1, B0, acc[1][0], 0, 0, 0); \
        acc[1][1] = __builtin_amdgcn_mfma_f32_16x16x32_f16(a1, B1, acc[1][1], 0, 0, 0); \
        acc[1][2] = __builtin_amdgcn_mfma_f32_16x16x32_f16(a1, B2, acc[1][2], 0, 0, 0); \
        acc[1][3] = __builtin_amdgcn_mfma_f32_16x16x32_f16(a1, B3, acc[1][3], 0, 0, 0); \
        acc[2][0] = __builtin_amdgcn_mfma_f32_16x16x32_f16(a2, B0, acc[2][0], 0, 0, 0); \
        acc[2][1] = __builtin_amdgcn_mfma_f32_16x16x32_f16(a2, B1, acc[2][1], 0, 0, 0); \
        acc[2][2] = __builtin_amdgcn_mfma_f32_16x16x32_f16(a2, B2, acc[2][2], 0, 0, 0); \
        acc[2][3] = __builtin_amdgcn_mfma_f32_16x16x32_f16(a2, B3, acc[2][3], 0, 0, 0); \
        acc[3][0] = __builtin_amdgcn_mfma_f32_16x16x32_f16(a3, B0, acc[3][0], 0, 0, 0); \
        acc[3][1] = __builtin_amdgcn_mfma_f32_16x16x32_f16(a3, B1, acc[3][1], 0, 0, 0); \
        acc[3][2] = __builtin_amdgcn_mfma_f32_16x16x32_f16(a3, B2, acc[3][2], 0, 0, 0); \
        acc[3][3] = __builtin_amdgcn_mfma_f32_16x16x32_f16(a3, B3, acc[3][3], 0, 0, 0); }

    LOAD_A(0); WRITE_A(0); LOAD_B(b0, b1, b2, b3, 0);
    __syncthreads();

    #pragma unroll 1
    for (int kt2 = 0; kt2 < NKT / 2; ++kt2) {
        const int kt = kt2 * 2;
        LOAD_A(kt + 1);
        LOAD_B(c0, c1, c2, c3, kt + 1);
        COMPUTE(0, b0, b1, b2, b3);
        WRITE_A(1);
        __syncthreads();
        if (kt2 < NKT / 2 - 1) {
            LOAD_A(kt + 2);
            LOAD_B(b0, b1, b2, b3, kt + 2);
        }
        COMPUTE(1, c0, c1, c2, c3);
        if (kt2 < NKT / 2 - 1) {
            WRITE_A(0);
        }
        __syncthreads();
    }

    const long orow0 = (long)bm * BMT + wm * 64 + lk * 4;
    const int  ocol0 = bn * BNT + wn * 64 + lr;
    #pragma unroll
    for (int mi = 0; mi < 4; ++mi)
        #pragma unroll
        for (int ni = 0; ni < 4; ++ni)
            #pragma unroll
            for (int q = 0; q < 4; ++q)
                out[(orow0 + mi * 16 + q) * 1024 + ocol0 + ni * 16] = acc[mi][ni][q];

#undef LOAD_A
#undef WRITE_A
#undef LOAD_B
#undef COMPUTE
}

// ===========================================================================
// Fallback (ws too small): R6's proven stencil kernel.
// ===========================================================================
#define RPB 16
#define MIX_L(acc, r32, ww) \
    asm("v_fma_mix_f32 %0, %1, %2, %0 op_sel:[0,0,0] op_sel_hi:[1,0,0]" \
        : "+v"(acc) : "v"(r32), "v"(ww))
#define MIX_H(acc, r32, ww) \
    asm("v_fma_mix_f32 %0, %1, %2, %0 op_sel:[1,0,0] op_sel_hi:[1,0,0]" \
        : "+v"(acc) : "v"(r32), "v"(ww))

__global__ __launch_bounds__(256, 2)
void butterfly_h16mix(const float* __restrict__ x,
                      const float* __restrict__ diag,
                      const float* __restrict__ subpad,
                      const float* __restrict__ suppad,
                      const float* __restrict__ logit,
                      float* __restrict__ out)
{
    __shared__ f16 buf[2][RPB][SIZE];
    const int tid = threadIdx.x;
    const int s0  = tid * 4;
    const long rowbase = (long)blockIdx.x * RPB;

    #pragma unroll
    for (int r = 0; r < RPB; ++r) {
        const float4 v = ldq(x + (rowbase + r) * SIZE + s0);
        f16x4 h;
        h[0] = (f16)v.x; h[1] = (f16)v.y; h[2] = (f16)v.z; h[3] = (f16)v.w;
        *(f16x4*)&buf[0][r][s0] = h;
    }
    __syncthreads();

    int cur = 0;
    for (int t = 0; t < NTERMS; ++t) {
        const int i = NTERMS - 1 - t;
        float lg[MM];
        float mx = -3.4e38f;
        #pragma unroll
        for (int j = 0; j < MM; ++j) { lg[j] = logit[i * MM + j]; mx = fmaxf(mx, lg[j]); }
        float ssum = 0.f;
        #pragma unroll
        for (int j = 0; j < MM; ++j) { lg[j] = __expf(lg[j] - mx); ssum += lg[j]; }
        const float inv = 1.0f / ssum;

        float D[4] = {0.f, 0.f, 0.f, 0.f};
        float Wsb[MM][4], Wsp[MM][4];
        #pragma unroll
        for (int j = 0; j < MM; ++j) {
            const float pj = lg[j] * inv;
            const float4 dg = ldq(diag   + j * SIZE + s0);
            const float4 sb = ldq(subpad + j * SIZE + s0);
            const float4 sp = ldq(suppad + j * SIZE + s0);
            D[0] = fmaf(pj, dg.x, D[0]); D[1] = fmaf(pj, dg.y, D[1]);
            D[2] = fmaf(pj, dg.z, D[2]); D[3] = fmaf(pj, dg.w, D[3]);
            Wsb[j][0] = pj * sb.x; Wsb[j][1] = pj * sb.y;
            Wsb[j][2] = pj * sb.z; Wsb[j][3] = pj * sb.w;
            Wsp[j][0] = pj * sp.x; Wsp[j][1] = pj * sp.y;
            Wsp[j][2] = pj * sp.z; Wsp[j][3] = pj * sp.w;
        }

        const bool last = (t == NTERMS - 1);
        for (int r = 0; r < RPB; ++r) {
            const f16* row = &buf[cur][r][0];
            const i2 xo = *(const i2*)&row[s0];
            const i2 xl = *(const i2*)&row[(s0 >= 4)        ? s0 - 4 : 0];
            const i2 xr = *(const i2*)&row[(s0 + 4 <= 1020) ? s0 + 4 : 1020];
            float a0 = 0.f, a1 = 0.f, a2 = 0.f, a3 = 0.f;

            MIX_L(a0, xo.x, D[0]); MIX_H(a1, xo.x, D[1]);
            MIX_L(a2, xo.y, D[2]); MIX_H(a3, xo.y, D[3]);
            MIX_H(a0, xl.y, Wsb[9][0]); MIX_L(a1, xo.x, Wsb[9][1]);
            MIX_H(a2, xo.x, Wsb[9][2]); MIX_L(a3, xo.y, Wsb[9][3]);
            MIX_H(a0, xo.x, Wsp[9][0]); MIX_L(a1, xo.y, Wsp[9][1]);
            MIX_H(a2, xo.y, Wsp[9][2]); MIX_L(a3, xr.x, Wsp[9][3]);
            MIX_L(a0, xl.y, Wsb[8][0]); MIX_H(a1, xl.y, Wsb[8][1]);
            MIX_L(a2, xo.x, Wsb[8][2]); MIX_H(a3, xo.x, Wsb[8][3]);
            MIX_L(a0, xo.y, Wsp[8][0]); MIX_H(a1, xo.y, Wsp[8][1]);
            MIX_L(a2, xr.x, Wsp[8][2]); MIX_H(a3, xr.x, Wsp[8][3]);
            MIX_L(a0, xl.x, Wsb[7][0]); MIX_H(a1, xl.x, Wsb[7][1]);
            MIX_L(a2, xl.y, Wsb[7][2]); MIX_H(a3, xl.y, Wsb[7][3]);
            MIX_L(a0, xr.x, Wsp[7][0]); MIX_H(a1, xr.x, Wsp[7][1]);
            MIX_L(a2, xr.y, Wsp[7][2]); MIX_H(a3, xr.y, Wsp[7][3]);
            #pragma unroll
            for (int j = 0; j <= 6; ++j) {
                const int d = 512 >> j;
                const i2 xm = *(const i2*)&row[(s0 >= d)        ? s0 - d : 0];
                const i2 xp = *(const i2*)&row[(s0 + d <= 1020) ? s0 + d : 1020];
                MIX_L(a0, xm.x, Wsb[j][0]); MIX_H(a1, xm.x, Wsb[j][1]);
                MIX_L(a2, xm.y, Wsb[j][2]); MIX_H(a3, xm.y, Wsb[j][3]);
                MIX_L(a0, xp.x, Wsp[j][0]); MIX_H(a1, xp.x, Wsp[j][1]);
                MIX_L(a2, xp.y, Wsp[j][2]); MIX_H(a3, xp.y, Wsp[j][3]);
            }

            if (last) {
                *(float4*)(out + (rowbase + r) * SIZE + s0) =
                    make_float4(a0, a1, a2, a3);
            } else {
                f16x4 hv;
                hv[0] = (f16)a0; hv[1] = (f16)a1; hv[2] = (f16)a2; hv[3] = (f16)a3;
                *(f16x4*)&buf[cur ^ 1][r][s0] = hv;
            }
        }
        __syncthreads();
        cur ^= 1;
    }
}

extern "C" void kernel_launch(void* const* d_in, const int* in_sizes, int n_in,
                              void* d_out, int out_size, void* d_ws, size_t ws_size,
                              hipStream_t stream) {
    const float* x      = (const float*)d_in[0];
    const float* diag   = (const float*)d_in[1];
    const float* subpad = (const float*)d_in[2];
    const float* suppad = (const float*)d_in[3];
    const float* logit  = (const float*)d_in[4];
    float* outp = (float*)d_out;

    const int batch = in_sizes[0] / SIZE;          // 8192
    const size_t needG  = (size_t)SIZE * SIZE * sizeof(float);  // 4 MB
    const size_t needGt = (size_t)SIZE * SIZE * sizeof(f16);    // 2 MB

    if (d_ws != nullptr && ws_size >= needG + needGt) {
        float* G  = (float*)d_ws;
        f16*   Gt = (f16*)((char*)d_ws + needG);
        precompute_G<<<dim3(SIZE), dim3(256), 0, stream>>>(
            diag, subpad, suppad, logit, G);
        transpose_cast<<<dim3(16, 16), dim3(256), 0, stream>>>(G, Gt);
        const int nblocks = (batch / BMT) * (SIZE / BNT);       // 512
        gemm_f16<<<dim3(nblocks), dim3(256), 0, stream>>>(x, Gt, outp);
    } else {
        butterfly_h16mix<<<dim3(batch / RPB), dim3(256), 0, stream>>>(
            x, diag, subpad, suppad, logit, outp);
    }
}